// Round 1
// baseline (32.603 us; speedup 1.0000x reference)
//
#include <hip/hip_runtime.h>

// Camera2World: out[b,n,i,h,w] = sum_j p2p[b,n,i,j] * hom_j
// where hom = [w*d, h*d, d, 1], i in {0,1,2}.
// Shapes: depth [4,6,512,960] f32, p2p [4,6,4,4] f32, out [4,6,3,512,960] f32.

namespace {
constexpr int B = 4, N = 6, H = 512, W = 960;
constexpr int HW = H * W;            // 491520
constexpr int VEC_PER_PLANE = HW / 4; // 122880
constexpr int W4 = W / 4;             // 240
}

__global__ __launch_bounds__(256)
void cam2world_kernel(const float* __restrict__ depth,
                      const float* __restrict__ p2p,
                      float* __restrict__ out) {
    const int bn = blockIdx.y;                       // 0..23, wave-uniform
    const int vec = blockIdx.x * 256 + threadIdx.x;  // 0..VEC_PER_PLANE-1
    if (vec >= VEC_PER_PLANE) return;

    // Per-plane 4x4 matrix: rows 0..2 needed. bn is uniform -> scalar loads.
    const float* __restrict__ m = p2p + bn * 16;
    const float m00 = m[0],  m01 = m[1],  m02 = m[2],  m03 = m[3];
    const float m10 = m[4],  m11 = m[5],  m12 = m[6],  m13 = m[7];
    const float m20 = m[8],  m21 = m[9],  m22 = m[10], m23 = m[11];

    const int h  = vec / W4;            // row (v)
    const int w4 = vec - h * W4;        // float4 index within row
    const int pix = h * W + w4 * 4;

    const float4 d = *reinterpret_cast<const float4*>(depth + (size_t)bn * HW + pix);

    const float v = (float)h;
    const float u0 = (float)(w4 * 4);

    // base_i = m_i1*v + m_i2  (constant across the 4 pixels of this thread)
    const float b0 = fmaf(m01, v, m02);
    const float b1 = fmaf(m11, v, m12);
    const float b2 = fmaf(m21, v, m22);

    float4 o0, o1, o2;
    {
        const float u = u0;
        o0.x = fmaf(d.x, fmaf(m00, u, b0), m03);
        o1.x = fmaf(d.x, fmaf(m10, u, b1), m13);
        o2.x = fmaf(d.x, fmaf(m20, u, b2), m23);
    }
    {
        const float u = u0 + 1.0f;
        o0.y = fmaf(d.y, fmaf(m00, u, b0), m03);
        o1.y = fmaf(d.y, fmaf(m10, u, b1), m13);
        o2.y = fmaf(d.y, fmaf(m20, u, b2), m23);
    }
    {
        const float u = u0 + 2.0f;
        o0.z = fmaf(d.z, fmaf(m00, u, b0), m03);
        o1.z = fmaf(d.z, fmaf(m10, u, b1), m13);
        o2.z = fmaf(d.z, fmaf(m20, u, b2), m23);
    }
    {
        const float u = u0 + 3.0f;
        o0.w = fmaf(d.w, fmaf(m00, u, b0), m03);
        o1.w = fmaf(d.w, fmaf(m10, u, b1), m13);
        o2.w = fmaf(d.w, fmaf(m20, u, b2), m23);
    }

    float* __restrict__ obase = out + (size_t)bn * 3 * HW + pix;
    *reinterpret_cast<float4*>(obase)          = o0;
    *reinterpret_cast<float4*>(obase + HW)     = o1;
    *reinterpret_cast<float4*>(obase + 2 * HW) = o2;
}

extern "C" void kernel_launch(void* const* d_in, const int* in_sizes, int n_in,
                              void* d_out, int out_size, void* d_ws, size_t ws_size,
                              hipStream_t stream) {
    const float* depth = (const float*)d_in[0];
    const float* p2p   = (const float*)d_in[1];
    float* out         = (float*)d_out;

    dim3 grid(VEC_PER_PLANE / 256, B * N);  // 480 x 24
    dim3 block(256);
    cam2world_kernel<<<grid, block, 0, stream>>>(depth, p2p, out);
}